// Round 1
// baseline (6896.892 us; speedup 1.0000x reference)
//
#include <hip/hip_runtime.h>

typedef _Float16 f16x8 __attribute__((ext_vector_type(8)));
typedef float f32x4 __attribute__((ext_vector_type(4)));

static constexpr int NL = 5;     // layers
static constexpr int NBATCH = 256;
static constexpr int NT = 128;   // timesteps
static constexpr int NH = 512;   // hidden
static constexpr int NG = 2048;  // 4*NH
static constexpr int NC = 40;    // classes

// ---------------------------------------------------------------------------
// fp32 -> fp16 conversion (grid-stride)
// ---------------------------------------------------------------------------
__global__ void f32_to_f16_kernel(const float* __restrict__ src,
                                  _Float16* __restrict__ dst, int n) {
  int i = blockIdx.x * blockDim.x + threadIdx.x;
  int stride = gridDim.x * blockDim.x;
  for (; i < n; i += stride) dst[i] = (_Float16)src[i];
}

// ---------------------------------------------------------------------------
// One pipeline slot s: layer l processes timestep t = s - l.
// Grid: 320 blocks = 4 m-blocks x 5 layers x 16 n-blocks, bid = mb*80 + l*16 + nb
// (stride-80 grouping keeps same-weight-slice blocks on one XCD).
// Block: 256 thr = 4 waves; wave w computes gate w for 64 batch x 32 h-units.
// G = h_in @ Wih^T + h_prev @ Whh^T  (two K=512 halves), fused cell update.
// ---------------------------------------------------------------------------
__global__ __launch_bounds__(256) void lstm_slot_kernel(
    const _Float16* __restrict__ wih_h, const _Float16* __restrict__ whh_h,
    const _Float16* __restrict__ x_h, const float* __restrict__ bih,
    const float* __restrict__ bhh, _Float16* __restrict__ h_xfer,
    float* __restrict__ c_state, int s) {
  const int bid = blockIdx.x;
  const int mb = bid / 80;
  const int rem = bid - mb * 80;
  const int layer = rem >> 4;
  const int nb = rem & 15;
  const int t = s - layer;
  if (t < 0 || t >= NT) return;

  const int tid = threadIdx.x;
  const int wv = tid >> 6;             // wave index == gate index (i,f,g,o)
  const int lane = tid & 63;
  const int lrow = lane & 15;
  const int lk = (lane >> 4) << 3;     // 0,8,16,24 (k sub-chunk)
  const int m0 = mb * 64;
  const int u0 = nb * 32;

  // A operand: layer input rows (batch-major). Layer 0 reads x, else prev layer h.
  const _Float16* aptr;
  size_t astride;
  if (layer == 0) {
    aptr = x_h + (size_t)t * NH;           // row b at b*T*NH + t*NH
    astride = (size_t)NT * NH;
  } else {
    aptr = h_xfer + (size_t)((layer - 1) * 2 + (t & 1)) * NBATCH * NH;
    astride = NH;
  }

  const _Float16* wih = wih_h + (size_t)layer * NG * NH;
  const _Float16* whh = whh_h + (size_t)layer * NG * NH;
  const int ncol = wv * NH + u0 + lrow;  // this lane's weight row (G column)

  f32x4 acc[4][2];
#pragma unroll
  for (int i = 0; i < 4; ++i)
#pragma unroll
    for (int j = 0; j < 2; ++j) acc[i][j] = (f32x4){0.f, 0.f, 0.f, 0.f};

  // ---- half 0: x_t (or h_in) @ Wih^T, K=512 ----
  {
    const _Float16* arow = aptr + (size_t)(m0 + lrow) * astride + lk;
    const _Float16* brow = wih + (size_t)ncol * NH + lk;
#pragma unroll 2
    for (int kk = 0; kk < 16; ++kk) {
      const int kc = kk << 5;
      f16x8 a0 = *(const f16x8*)(arow + kc);
      f16x8 a1 = *(const f16x8*)(arow + 16 * astride + kc);
      f16x8 a2 = *(const f16x8*)(arow + 32 * astride + kc);
      f16x8 a3 = *(const f16x8*)(arow + 48 * astride + kc);
      f16x8 b0 = *(const f16x8*)(brow + kc);
      f16x8 b1 = *(const f16x8*)(brow + 16 * NH + kc);
      acc[0][0] = __builtin_amdgcn_mfma_f32_16x16x32_f16(a0, b0, acc[0][0], 0, 0, 0);
      acc[1][0] = __builtin_amdgcn_mfma_f32_16x16x32_f16(a1, b0, acc[1][0], 0, 0, 0);
      acc[2][0] = __builtin_amdgcn_mfma_f32_16x16x32_f16(a2, b0, acc[2][0], 0, 0, 0);
      acc[3][0] = __builtin_amdgcn_mfma_f32_16x16x32_f16(a3, b0, acc[3][0], 0, 0, 0);
      acc[0][1] = __builtin_amdgcn_mfma_f32_16x16x32_f16(a0, b1, acc[0][1], 0, 0, 0);
      acc[1][1] = __builtin_amdgcn_mfma_f32_16x16x32_f16(a1, b1, acc[1][1], 0, 0, 0);
      acc[2][1] = __builtin_amdgcn_mfma_f32_16x16x32_f16(a2, b1, acc[2][1], 0, 0, 0);
      acc[3][1] = __builtin_amdgcn_mfma_f32_16x16x32_f16(a3, b1, acc[3][1], 0, 0, 0);
    }
  }

  // ---- half 1: h_prev @ Whh^T, K=512 (skip at t=0: h_prev == 0) ----
  if (t > 0) {
    const _Float16* hp =
        h_xfer + (size_t)(layer * 2 + ((t + 1) & 1)) * NBATCH * NH;
    const _Float16* arow = hp + (size_t)(m0 + lrow) * NH + lk;
    const _Float16* brow = whh + (size_t)ncol * NH + lk;
#pragma unroll 2
    for (int kk = 0; kk < 16; ++kk) {
      const int kc = kk << 5;
      f16x8 a0 = *(const f16x8*)(arow + kc);
      f16x8 a1 = *(const f16x8*)(arow + 16 * NH + kc);
      f16x8 a2 = *(const f16x8*)(arow + 32 * NH + kc);
      f16x8 a3 = *(const f16x8*)(arow + 48 * NH + kc);
      f16x8 b0 = *(const f16x8*)(brow + kc);
      f16x8 b1 = *(const f16x8*)(brow + 16 * NH + kc);
      acc[0][0] = __builtin_amdgcn_mfma_f32_16x16x32_f16(a0, b0, acc[0][0], 0, 0, 0);
      acc[1][0] = __builtin_amdgcn_mfma_f32_16x16x32_f16(a1, b0, acc[1][0], 0, 0, 0);
      acc[2][0] = __builtin_amdgcn_mfma_f32_16x16x32_f16(a2, b0, acc[2][0], 0, 0, 0);
      acc[3][0] = __builtin_amdgcn_mfma_f32_16x16x32_f16(a3, b0, acc[3][0], 0, 0, 0);
      acc[0][1] = __builtin_amdgcn_mfma_f32_16x16x32_f16(a0, b1, acc[0][1], 0, 0, 0);
      acc[1][1] = __builtin_amdgcn_mfma_f32_16x16x32_f16(a1, b1, acc[1][1], 0, 0, 0);
      acc[2][1] = __builtin_amdgcn_mfma_f32_16x16x32_f16(a2, b1, acc[2][1], 0, 0, 0);
      acc[3][1] = __builtin_amdgcn_mfma_f32_16x16x32_f16(a3, b1, acc[3][1], 0, 0, 0);
    }
  }

  // ---- exchange gates through LDS: gsm[batch_row][gate*32 + u_local] ----
  __shared__ float gsm[64][132];  // pad 128->132 to break bank alignment
  const int r0 = (lane >> 4) << 2;
#pragma unroll
  for (int mt = 0; mt < 4; ++mt)
#pragma unroll
    for (int nt = 0; nt < 2; ++nt) {
#pragma unroll
      for (int r = 0; r < 4; ++r)
        gsm[mt * 16 + r0 + r][(wv << 5) + (nt << 4) + lrow] = acc[mt][nt][r];
    }
  __syncthreads();

  // ---- fused LSTM cell update: thread -> (1 batch row, 8 h-units) ----
  const int ml = tid >> 2;             // 0..63 batch row within block
  const int uq = (tid & 3) << 3;       // 0,8,16,24
  const int b = m0 + ml;
  const float* bi = bih + layer * NG;
  const float* bh = bhh + layer * NG;
  float* cs = c_state + ((size_t)layer * NBATCH + b) * NH;
  _Float16* hout =
      h_xfer + ((size_t)(layer * 2 + (t & 1)) * NBATCH + b) * NH;
#pragma unroll
  for (int j = 0; j < 8; ++j) {
    const int ul = uq + j;
    const int u = u0 + ul;
    float gi = gsm[ml][ul] + bi[u] + bh[u];
    float gf = gsm[ml][32 + ul] + bi[NH + u] + bh[NH + u];
    float gg = gsm[ml][64 + ul] + bi[2 * NH + u] + bh[2 * NH + u];
    float go = gsm[ml][96 + ul] + bi[3 * NH + u] + bh[3 * NH + u];
    float cp = (t == 0) ? 0.f : cs[u];
    float is = 1.f / (1.f + __expf(-gi));
    float fs = 1.f / (1.f + __expf(-gf));
    float gt = 2.f / (1.f + __expf(-2.f * gg)) - 1.f;
    float os = 1.f / (1.f + __expf(-go));
    float c = fs * cp + is * gt;
    cs[u] = c;
    float th = 2.f / (1.f + __expf(-2.f * c)) - 1.f;
    hout[u] = (_Float16)(os * th);
  }
}

// ---------------------------------------------------------------------------
// Final FC: out[b][c] = h_last[b] . Wfc[c] + bfc[c]   (fp32 accumulate)
// ---------------------------------------------------------------------------
__global__ __launch_bounds__(64) void fc_kernel(
    const _Float16* __restrict__ h_xfer, const float* __restrict__ wfc,
    const float* __restrict__ bfc, float* __restrict__ out) {
  // layer 4 output at t=127 lives in parity slot (127 & 1) == 1
  const _Float16* h = h_xfer + (size_t)(4 * 2 + 1) * NBATCH * NH;
  const int b = blockIdx.x;
  const int lane = threadIdx.x;
  __shared__ float hrow[NH];
  for (int k = lane; k < NH; k += 64) hrow[k] = (float)h[(size_t)b * NH + k];
  __syncthreads();
  if (lane < NC) {
    const float* w = wfc + (size_t)lane * NH;
    float acc = bfc[lane];
#pragma unroll 8
    for (int k = 0; k < NH; ++k) acc += hrow[k] * w[k];
    out[b * NC + lane] = acc;
  }
}

// ---------------------------------------------------------------------------
extern "C" void kernel_launch(void* const* d_in, const int* in_sizes, int n_in,
                              void* d_out, int out_size, void* d_ws,
                              size_t ws_size, hipStream_t stream) {
  const float* x = (const float*)d_in[0];
  const float* Wih = (const float*)d_in[1];
  const float* Whh = (const float*)d_in[2];
  const float* bih = (const float*)d_in[3];
  const float* bhh = (const float*)d_in[4];
  const float* Wfc = (const float*)d_in[5];
  const float* bfc = (const float*)d_in[6];
  float* out = (float*)d_out;

  char* ws = (char*)d_ws;
  size_t off = 0;
  _Float16* wih_h = (_Float16*)(ws + off); off += (size_t)NL * NG * NH * 2;
  _Float16* whh_h = (_Float16*)(ws + off); off += (size_t)NL * NG * NH * 2;
  _Float16* x_h   = (_Float16*)(ws + off); off += (size_t)NBATCH * NT * NH * 2;
  _Float16* h_xfer = (_Float16*)(ws + off); off += (size_t)NL * 2 * NBATCH * NH * 2;
  float* c_st = (float*)(ws + off); off += (size_t)NL * NBATCH * NH * 4;

  f32_to_f16_kernel<<<1024, 256, 0, stream>>>(Wih, wih_h, NL * NG * NH);
  f32_to_f16_kernel<<<1024, 256, 0, stream>>>(Whh, whh_h, NL * NG * NH);
  f32_to_f16_kernel<<<2048, 256, 0, stream>>>(x, x_h, NBATCH * NT * NH);

  // Wavefront pipeline over slots s = t + layer.
  for (int s = 0; s < NT + NL - 1; ++s)
    lstm_slot_kernel<<<320, 256, 0, stream>>>(wih_h, whh_h, x_h, bih, bhh,
                                              h_xfer, c_st, s);

  fc_kernel<<<NBATCH, 64, 0, stream>>>(h_xfer, Wfc, bfc, out);
}